// Round 7
// baseline (185.887 us; speedup 1.0000x reference)
//
#include <hip/hip_runtime.h>
#include <math.h>

#define S_ 3
#define G_ 8
#define B_ 2048
#define C_ 512
#define P_ 64
#define N_ (S_ * G_ * B_)   // 49152

typedef __attribute__((ext_vector_type(8))) short short8;
typedef __attribute__((ext_vector_type(4))) float f32x4;
typedef __attribute__((ext_vector_type(4))) unsigned int uint4v;

__device__ __forceinline__ unsigned f2bf1(float f) {
    union { float f; unsigned u; } c; c.f = f;
    unsigned u = c.u;
    u += 0x7fffu + ((u >> 16) & 1u);   // RNE
    return u >> 16;
}
__device__ __forceinline__ unsigned pk2(float a, float b) {
    return f2bf1(a) | (f2bf1(b) << 16);
}
// async global->LDS, 16B/lane; LDS dest = wave-uniform base + lane*16
__device__ __forceinline__ void gl_lds16(const void* g, void* l) {
    __builtin_amdgcn_global_load_lds(
        (const __attribute__((address_space(1))) void*)g,
        (__attribute__((address_space(3))) void*)l, 16, 0, 0);
}
// CK-style split barrier: wait only the oldest loads, raw s_barrier (no drain)
#define WAIT6_BARRIER() asm volatile("s_waitcnt vmcnt(6)\n\ts_barrier" ::: "memory")
#define WAIT0_BARRIER() asm volatile("s_waitcnt vmcnt(0)\n\ts_barrier" ::: "memory")
#define RAW_BARRIER()   asm volatile("s_barrier" ::: "memory")

// ---------------------------------------------------------------------------
// prep: w -> bf16 row-major, csq[p], rbeta[p] = 1/sigmoid(sf)
// ---------------------------------------------------------------------------
__global__ __launch_bounds__(64) void prep_kernel(
    const float* __restrict__ w, const float* __restrict__ sf,
    unsigned short* __restrict__ wb, float* __restrict__ csq,
    float* __restrict__ rbeta)
{
    const int p = blockIdx.x, l = threadIdx.x;
    const float* wr = w + (size_t)p * C_ + l * 8;
    f32x4 a = *(const f32x4*)wr;
    f32x4 b = *(const f32x4*)(wr + 4);
    float s = a[0]*a[0] + a[1]*a[1] + a[2]*a[2] + a[3]*a[3]
            + b[0]*b[0] + b[1]*b[1] + b[2]*b[2] + b[3]*b[3];
    uint4v pk;
    pk.x = pk2(a[0], a[1]); pk.y = pk2(a[2], a[3]);
    pk.z = pk2(b[0], b[1]); pk.w = pk2(b[2], b[3]);
    *(uint4v*)&wb[(size_t)p * C_ + l * 8] = pk;
#pragma unroll
    for (int off = 1; off < 64; off <<= 1) s += __shfl_xor(s, off, 64);
    if (l == 0) csq[p] = s;
    if (p == 0) rbeta[l] = 1.0f + expf(-sf[l]);
}

// ---------------------------------------------------------------------------
// assign_v7: 768 blocks x 256 thr, 64 rows, BK=64, all-gl_lds double buffer
// with split barriers (vmcnt(6) + raw s_barrier) so next chunk's 6 loads/wave
// stay in flight across the whole compute phase.
// x: no-pad fp32 [row][64], granule swizzle pr(row)=((row>>1)&7)|(row&8).
// w: no-pad bf16 [p][64], granule swizzle (p&7). Both frag-read at bank floor.
// ---------------------------------------------------------------------------
__global__ __launch_bounds__(256, 3) void assign_v7(
    const float* __restrict__ x, const unsigned short* __restrict__ wb,
    const float* __restrict__ csq, const float* __restrict__ rbeta,
    float* __restrict__ assign, unsigned short* __restrict__ a_t)
{
    __shared__ __align__(16) float xsb[2][64 * 64];          // 32 KB
    __shared__ __align__(16) unsigned short wsb[2][64 * 64]; // 16 KB
    __shared__ float xsq_s[64];
    float* lg = &xsb[0][0];   // epilogue alias [64][68] fp32 (17.4 KB < 32 KB)

    const int t = threadIdx.x, lane = t & 63, wv = t >> 6;
    const int q = lane >> 4, col = lane & 15;
    const int n0 = blockIdx.x * 64;

    // staging pointers: x 4 instr/wave (4 rows each), w 2 instr/wave (8 rows)
    const float* gx[4];
#pragma unroll
    for (int i = 0; i < 4; ++i) {
        const int row = 16 * wv + 4 * i + (lane >> 4);
        const int pr  = ((row >> 1) & 7) | (row & 8);
        gx[i] = x + (size_t)(n0 + row) * C_ + (((lane & 15) ^ pr) << 2);
    }
    const unsigned short* gw[2];
#pragma unroll
    for (int i = 0; i < 2; ++i) {
        const int p = 16 * wv + 8 * i + (lane >> 3);
        gw[i] = wb + (size_t)p * C_ + (((lane & 7) ^ (p & 7)) * 8);
    }
    const int prA = ((col >> 1) & 7) | (col & 8);
    const int wg  = col & 7;

    float csqv[4], rbv[4];
#pragma unroll
    for (int nt = 0; nt < 4; ++nt) {
        csqv[nt] = csq[16 * nt + col];
        rbv[nt]  = rbeta[16 * nt + col];
    }

    f32x4 acc[4];
#pragma unroll
    for (int nt = 0; nt < 4; ++nt) acc[nt] = (f32x4){0.f, 0.f, 0.f, 0.f};
    float xsq = 0.f;

    // prologue: chunk 0 in flight (6 loads/wave)
#pragma unroll
    for (int i = 0; i < 4; ++i) gl_lds16(gx[i], &xsb[0][(16 * wv + 4 * i) * 64]);
#pragma unroll
    for (int i = 0; i < 2; ++i) gl_lds16(gw[i], &wsb[0][(16 * wv + 8 * i) * 64]);

#pragma unroll
    for (int ch = 0; ch < 8; ++ch) {
        const int cur = ch & 1;
        if (ch < 7) {
            const int k0 = (ch + 1) * 64;
#pragma unroll
            for (int i = 0; i < 4; ++i)
                gl_lds16(gx[i] + k0, &xsb[cur ^ 1][(16 * wv + 4 * i) * 64]);
#pragma unroll
            for (int i = 0; i < 2; ++i)
                gl_lds16(gw[i] + k0, &wsb[cur ^ 1][(16 * wv + 8 * i) * 64]);
            WAIT6_BARRIER();   // cur landed; next 6 stay in flight
        } else {
            WAIT0_BARRIER();
        }
#pragma unroll
        for (int s = 0; s < 2; ++s) {
            const int g0 = 8 * s + 2 * q;
            f32x4 f0 = *(const f32x4*)&xsb[cur][(16 * wv + col) * 64 + ((g0 ^ prA) << 2)];
            f32x4 f1 = *(const f32x4*)&xsb[cur][(16 * wv + col) * 64 + (((g0 + 1) ^ prA) << 2)];
            xsq += f0.x*f0.x + f0.y*f0.y + f0.z*f0.z + f0.w*f0.w
                 + f1.x*f1.x + f1.y*f1.y + f1.z*f1.z + f1.w*f1.w;
            union { uint4v u; short8 s8; } cv;
            cv.u.x = pk2(f0.x, f0.y); cv.u.y = pk2(f0.z, f0.w);
            cv.u.z = pk2(f1.x, f1.y); cv.u.w = pk2(f1.z, f1.w);
            const int wgr = 4 * s + q;
#pragma unroll
            for (int nt = 0; nt < 4; ++nt) {
                short8 bf = *(const short8*)&wsb[cur][(16 * nt + col) * 64 + ((wgr ^ wg) * 8)];
                acc[nt] = __builtin_amdgcn_mfma_f32_16x16x32_bf16(cv.s8, bf, acc[nt], 0, 0, 0);
            }
        }
        RAW_BARRIER();   // all waves done reading buf[cur] before it's rewritten
    }

    // |x|^2: lane holds its q-quarter of row 16wv+col -> reduce over q
    xsq += __shfl_xor(xsq, 16, 64);
    xsq += __shfl_xor(xsq, 32, 64);
    if (q == 0) xsq_s[16 * wv + col] = xsq;
    __syncthreads();

    // logits + softmax (shuffle over 16-lane groups)
    float vals[4][4];
#pragma unroll
    for (int reg = 0; reg < 4; ++reg) {
        const int row = 16 * wv + 4 * q + reg;
        const float xq = xsq_s[row];
        float vmax = -3.4e38f;
#pragma unroll
        for (int nt = 0; nt < 4; ++nt) {
            float v = 2.0f * acc[nt][reg] - xq - csqv[nt];
            v = fminf(v, 0.0f) * rbv[nt];
            vals[reg][nt] = v;
            vmax = fmaxf(vmax, v);
        }
#pragma unroll
        for (int off = 1; off < 16; off <<= 1)
            vmax = fmaxf(vmax, __shfl_xor(vmax, off, 64));
        float ss = 0.f;
#pragma unroll
        for (int nt = 0; nt < 4; ++nt) { vals[reg][nt] = __expf(vals[reg][nt] - vmax); ss += vals[reg][nt]; }
#pragma unroll
        for (int off = 1; off < 16; off <<= 1)
            ss += __shfl_xor(ss, off, 64);
        const float inv = 1.0f / ss;
#pragma unroll
        for (int nt = 0; nt < 4; ++nt) vals[reg][nt] *= inv;
    }

    // stage result tile in LDS (lg aliases xsb, dead after loop)
#pragma unroll
    for (int reg = 0; reg < 4; ++reg) {
        const int row = 16 * wv + 4 * q + reg;
#pragma unroll
        for (int nt = 0; nt < 4; ++nt)
            lg[row * 68 + 16 * nt + col] = vals[reg][nt];
    }
    __syncthreads();

    // coalesced fp32 assign write
#pragma unroll
    for (int i = 0; i < 4; ++i) {
        const int f = i * 256 + t;
        const int row = f >> 4, sp = (f & 15) * 4;
        *(f32x4*)(assign + (size_t)(n0 + row) * P_ + sp) = *(const f32x4*)&lg[row * 68 + sp];
    }

    // transposed bf16 a_t[p][n]: thread (p = lane, n-quarter = wv)
    const int p = lane;
    float v[16];
#pragma unroll
    for (int i = 0; i < 16; ++i) v[i] = lg[(wv * 16 + i) * 68 + p];
    uint4v d0, d1;
    d0.x = pk2(v[0], v[1]);   d0.y = pk2(v[2], v[3]);
    d0.z = pk2(v[4], v[5]);   d0.w = pk2(v[6], v[7]);
    d1.x = pk2(v[8], v[9]);   d1.y = pk2(v[10], v[11]);
    d1.z = pk2(v[12], v[13]); d1.w = pk2(v[14], v[15]);
    unsigned short* dst = a_t + (size_t)p * N_ + n0 + wv * 16;
    *(uint4v*)dst = d0;
    *(uint4v*)(dst + 8) = d1;
}

// ---------------------------------------------------------------------------
// group_v7: partials[g,ct,ks][p][c] = sum_n a[n,p] x[n,c]. Grid (8,8,12).
// Same split-barrier gl_lds pipeline (x 4 + a 2 loads/wave/chunk).
// a_t: no-pad bf16 [p][64n], granule swizzle (p&7) -> A-frag b128 bank floor.
// x:   no-pad fp32 [n][64c], v6 granule swizzle -> b32 gathers 2-way floor.
// ---------------------------------------------------------------------------
__global__ __launch_bounds__(256, 3) void group_v7(
    const float* __restrict__ x, const unsigned short* __restrict__ a_t,
    float* __restrict__ part)
{
    __shared__ __align__(16) float xsb[2][64 * 64];           // 32 KB
    __shared__ __align__(16) unsigned short asb[2][64 * 64];  // 16 KB

    const int t = threadIdx.x, lane = t & 63, wv = t >> 6;
    const int q = lane >> 4, col = lane & 15;
    const int g = blockIdx.x, ct = blockIdx.y, ks = blockIdx.z;
    const int c0 = ct * 64, sc = ks >> 2, b0 = (ks & 3) * 512;
    const size_t base = (size_t)sc * (G_ * B_) + (size_t)g * B_ + b0;

    const float* gx[4];
#pragma unroll
    for (int i = 0; i < 4; ++i) {
        const int n  = 16 * wv + 4 * i + (lane >> 4);
        const int pm = ((n >> 3) & 3) | (((n >> 3) & 1) << 2);
        gx[i] = x + (base + n) * C_ + c0 + (((lane & 15) ^ pm) << 2);
    }
    const unsigned short* ga[2];
#pragma unroll
    for (int i = 0; i < 2; ++i) {
        const int p = 16 * wv + 8 * i + (lane >> 3);
        ga[i] = a_t + (size_t)p * N_ + base + (((lane & 7) ^ (p & 7)) * 8);
    }
    const int cl = 16 * wv + col;
    const int permq = q | ((q & 1) << 2);
    const int cswz  = (((cl >> 2) ^ permq) << 2) | (cl & 3);
    const int ag    = col & 7;

    f32x4 acc[4];
#pragma unroll
    for (int mt = 0; mt < 4; ++mt) acc[mt] = (f32x4){0.f, 0.f, 0.f, 0.f};

    // prologue
#pragma unroll
    for (int i = 0; i < 4; ++i) gl_lds16(gx[i], &xsb[0][(16 * wv + 4 * i) * 64]);
#pragma unroll
    for (int i = 0; i < 2; ++i) gl_lds16(ga[i], &asb[0][(16 * wv + 8 * i) * 64]);

#pragma unroll
    for (int ch = 0; ch < 8; ++ch) {
        const int cur = ch & 1;
        if (ch < 7) {
            const int nb = (ch + 1) * 64;
#pragma unroll
            for (int i = 0; i < 4; ++i)
                gl_lds16(gx[i] + (size_t)nb * C_, &xsb[cur ^ 1][(16 * wv + 4 * i) * 64]);
#pragma unroll
            for (int i = 0; i < 2; ++i)
                gl_lds16(ga[i] + nb, &asb[cur ^ 1][(16 * wv + 8 * i) * 64]);
            WAIT6_BARRIER();
        } else {
            WAIT0_BARRIER();
        }
#pragma unroll
        for (int s = 0; s < 2; ++s) {
            const int koff = s * 32 + q * 8;
            float gv[8];
#pragma unroll
            for (int j = 0; j < 8; ++j) gv[j] = xsb[cur][(koff + j) * 64 + cswz];
            union { uint4v u; short8 s8; } cv;
            cv.u.x = pk2(gv[0], gv[1]); cv.u.y = pk2(gv[2], gv[3]);
            cv.u.z = pk2(gv[4], gv[5]); cv.u.w = pk2(gv[6], gv[7]);
            const int agr = 4 * s + q;
#pragma unroll
            for (int mt = 0; mt < 4; ++mt) {
                short8 af = *(const short8*)&asb[cur][(16 * mt + col) * 64 + ((agr ^ ag) * 8)];
                acc[mt] = __builtin_amdgcn_mfma_f32_16x16x32_bf16(af, cv.s8, acc[mt], 0, 0, 0);
            }
        }
        RAW_BARRIER();
    }

    // per-block partial tile (plain stores; reduced by reduce_out)
    float* pt = part + (((size_t)(g * 8 + ct) * 12) + ks) * 4096;
#pragma unroll
    for (int mt = 0; mt < 4; ++mt)
#pragma unroll
        for (int reg = 0; reg < 4; ++reg) {
            const int p = 16 * mt + 4 * q + reg;
            pt[p * 64 + cl] = acc[mt][reg];
        }
}

// ---------------------------------------------------------------------------
// reduce_out: out[g,p,c] = sum_{ks=0..11} part[g,ct,ks][p][cl]
// ---------------------------------------------------------------------------
__global__ __launch_bounds__(256) void reduce_out(
    const float* __restrict__ part, float* __restrict__ out)
{
    const int idx = blockIdx.x * 256 + threadIdx.x;   // 262144 total
    const int g = idx >> 15, r = idx & 32767;
    const int p = r >> 9,  c = r & 511;
    const int ct = c >> 6, cl = c & 63;
    const float* src = part + (((size_t)(g * 8 + ct) * 12)) * 4096 + p * 64 + cl;
    float s = 0.f;
#pragma unroll
    for (int ks = 0; ks < 12; ++ks) s += src[(size_t)ks * 4096];
    out[idx] = s;
}

// ---------------------------------------------------------------------------
extern "C" void kernel_launch(void* const* d_in, const int* in_sizes, int n_in,
                              void* d_out, int out_size, void* d_ws, size_t ws_size,
                              hipStream_t stream) {
    const float* x  = (const float*)d_in[0];   // node_feats [3, 16384, 512]
    const float* w  = (const float*)d_in[1];   // weight [64, 512]
    const float* sf = (const float*)d_in[2];   // smooth_factor [64]

    float* out    = (float*)d_out;              // outputs [8, 64, 512]
    float* assign = out + (size_t)G_ * P_ * C_; // assign [N, 64] fp32

    unsigned short* wb    = (unsigned short*)d_ws;                   // 64 KB
    float*          csq   = (float*)((char*)d_ws + 65536);           // 256 B
    float*          rbeta = (float*)((char*)d_ws + 65792);           // 256 B
    unsigned short* a_t   = (unsigned short*)((char*)d_ws + 66048);  // 6.29 MB
    float*          part  = (float*)((char*)d_ws + 6553600);         // 12.6 MB

    prep_kernel<<<P_, 64, 0, stream>>>(w, sf, wb, csq, rbeta);
    assign_v7<<<N_ / 64, 256, 0, stream>>>(x, wb, csq, rbeta, assign, a_t);
    dim3 gridB(G_, C_ / 64, 12);
    group_v7<<<gridB, 256, 0, stream>>>(x, a_t, part);
    reduce_out<<<(G_ * P_ * C_) / 256, 256, 0, stream>>>(part, out);
}

// Round 8
// 183.060 us; speedup vs baseline: 1.0154x; 1.0154x over previous
//
#include <hip/hip_runtime.h>
#include <math.h>

#define S_ 3
#define G_ 8
#define B_ 2048
#define C_ 512
#define P_ 64
#define N_ (S_ * G_ * B_)   // 49152

typedef __attribute__((ext_vector_type(8))) short short8;
typedef __attribute__((ext_vector_type(4))) float f32x4;
typedef __attribute__((ext_vector_type(4))) unsigned int uint4v;

__device__ __forceinline__ unsigned f2bf1(float f) {
    union { float f; unsigned u; } c; c.f = f;
    unsigned u = c.u;
    u += 0x7fffu + ((u >> 16) & 1u);   // RNE
    return u >> 16;
}
__device__ __forceinline__ unsigned pk2(float a, float b) {
    return f2bf1(a) | (f2bf1(b) << 16);
}
// async global->LDS, 16B/lane; LDS dest = wave-uniform base + lane*16
__device__ __forceinline__ void gl_lds16(const void* g, void* l) {
    __builtin_amdgcn_global_load_lds(
        (const __attribute__((address_space(1))) void*)g,
        (__attribute__((address_space(3))) void*)l, 16, 0, 0);
}
#define WAIT6_BARRIER() asm volatile("s_waitcnt vmcnt(6)\n\ts_barrier" ::: "memory")
#define WAIT0_BARRIER() asm volatile("s_waitcnt vmcnt(0)\n\ts_barrier" ::: "memory")
#define RAW_BARRIER()   asm volatile("s_barrier" ::: "memory")

// ---------------------------------------------------------------------------
// prep2: w -> bf16 row-major, csq[p], rbeta[p] = 1/sigmoid(sf); ALSO zeros
// the outputs region (16 KB per block) so no separate zero kernel is needed.
// ---------------------------------------------------------------------------
__global__ __launch_bounds__(64) void prep2_kernel(
    const float* __restrict__ w, const float* __restrict__ sf,
    unsigned short* __restrict__ wb, float* __restrict__ csq,
    float* __restrict__ rbeta, float* __restrict__ out)
{
    const int p = blockIdx.x, l = threadIdx.x;

    // zero out-slice: 4096 floats per block
    f32x4* oz = (f32x4*)(out + (size_t)p * 4096);
#pragma unroll
    for (int i = 0; i < 16; ++i) oz[i * 64 + l] = (f32x4){0.f, 0.f, 0.f, 0.f};

    const float* wr = w + (size_t)p * C_ + l * 8;
    f32x4 a = *(const f32x4*)wr;
    f32x4 b = *(const f32x4*)(wr + 4);
    float s = a[0]*a[0] + a[1]*a[1] + a[2]*a[2] + a[3]*a[3]
            + b[0]*b[0] + b[1]*b[1] + b[2]*b[2] + b[3]*b[3];
    uint4v pk;
    pk.x = pk2(a[0], a[1]); pk.y = pk2(a[2], a[3]);
    pk.z = pk2(b[0], b[1]); pk.w = pk2(b[2], b[3]);
    *(uint4v*)&wb[(size_t)p * C_ + l * 8] = pk;
#pragma unroll
    for (int off = 1; off < 64; off <<= 1) s += __shfl_xor(s, off, 64);
    if (l == 0) csq[p] = s;
    if (p == 0) rbeta[l] = 1.0f + expf(-sf[l]);
}

// ---------------------------------------------------------------------------
// assign_v8 (== proven assign_v7): 768 blocks x 256 thr, 64 rows, BK=64,
// all-gl_lds double buffer with split barriers.
// x: no-pad fp32 [row][64], granule swizzle pr(row)=((row>>1)&7)|(row&8).
// w: no-pad bf16 [p][64], granule swizzle (p&7).
// ---------------------------------------------------------------------------
__global__ __launch_bounds__(256, 3) void assign_v8(
    const float* __restrict__ x, const unsigned short* __restrict__ wb,
    const float* __restrict__ csq, const float* __restrict__ rbeta,
    float* __restrict__ assign, unsigned short* __restrict__ a_t)
{
    __shared__ __align__(16) float xsb[2][64 * 64];          // 32 KB
    __shared__ __align__(16) unsigned short wsb[2][64 * 64]; // 16 KB
    __shared__ float xsq_s[64];
    float* lg = &xsb[0][0];   // epilogue alias [64][68] fp32

    const int t = threadIdx.x, lane = t & 63, wv = t >> 6;
    const int q = lane >> 4, col = lane & 15;
    const int n0 = blockIdx.x * 64;

    const float* gx[4];
#pragma unroll
    for (int i = 0; i < 4; ++i) {
        const int row = 16 * wv + 4 * i + (lane >> 4);
        const int pr  = ((row >> 1) & 7) | (row & 8);
        gx[i] = x + (size_t)(n0 + row) * C_ + (((lane & 15) ^ pr) << 2);
    }
    const unsigned short* gw[2];
#pragma unroll
    for (int i = 0; i < 2; ++i) {
        const int p = 16 * wv + 8 * i + (lane >> 3);
        gw[i] = wb + (size_t)p * C_ + (((lane & 7) ^ (p & 7)) * 8);
    }
    const int prA = ((col >> 1) & 7) | (col & 8);
    const int wg  = col & 7;

    float csqv[4], rbv[4];
#pragma unroll
    for (int nt = 0; nt < 4; ++nt) {
        csqv[nt] = csq[16 * nt + col];
        rbv[nt]  = rbeta[16 * nt + col];
    }

    f32x4 acc[4];
#pragma unroll
    for (int nt = 0; nt < 4; ++nt) acc[nt] = (f32x4){0.f, 0.f, 0.f, 0.f};
    float xsq = 0.f;

#pragma unroll
    for (int i = 0; i < 4; ++i) gl_lds16(gx[i], &xsb[0][(16 * wv + 4 * i) * 64]);
#pragma unroll
    for (int i = 0; i < 2; ++i) gl_lds16(gw[i], &wsb[0][(16 * wv + 8 * i) * 64]);

#pragma unroll
    for (int ch = 0; ch < 8; ++ch) {
        const int cur = ch & 1;
        if (ch < 7) {
            const int k0 = (ch + 1) * 64;
#pragma unroll
            for (int i = 0; i < 4; ++i)
                gl_lds16(gx[i] + k0, &xsb[cur ^ 1][(16 * wv + 4 * i) * 64]);
#pragma unroll
            for (int i = 0; i < 2; ++i)
                gl_lds16(gw[i] + k0, &wsb[cur ^ 1][(16 * wv + 8 * i) * 64]);
            WAIT6_BARRIER();
        } else {
            WAIT0_BARRIER();
        }
#pragma unroll
        for (int s = 0; s < 2; ++s) {
            const int g0 = 8 * s + 2 * q;
            f32x4 f0 = *(const f32x4*)&xsb[cur][(16 * wv + col) * 64 + ((g0 ^ prA) << 2)];
            f32x4 f1 = *(const f32x4*)&xsb[cur][(16 * wv + col) * 64 + (((g0 + 1) ^ prA) << 2)];
            xsq += f0.x*f0.x + f0.y*f0.y + f0.z*f0.z + f0.w*f0.w
                 + f1.x*f1.x + f1.y*f1.y + f1.z*f1.z + f1.w*f1.w;
            union { uint4v u; short8 s8; } cv;
            cv.u.x = pk2(f0.x, f0.y); cv.u.y = pk2(f0.z, f0.w);
            cv.u.z = pk2(f1.x, f1.y); cv.u.w = pk2(f1.z, f1.w);
            const int wgr = 4 * s + q;
#pragma unroll
            for (int nt = 0; nt < 4; ++nt) {
                short8 bf = *(const short8*)&wsb[cur][(16 * nt + col) * 64 + ((wgr ^ wg) * 8)];
                acc[nt] = __builtin_amdgcn_mfma_f32_16x16x32_bf16(cv.s8, bf, acc[nt], 0, 0, 0);
            }
        }
        RAW_BARRIER();
    }

    xsq += __shfl_xor(xsq, 16, 64);
    xsq += __shfl_xor(xsq, 32, 64);
    if (q == 0) xsq_s[16 * wv + col] = xsq;
    __syncthreads();

    float vals[4][4];
#pragma unroll
    for (int reg = 0; reg < 4; ++reg) {
        const int row = 16 * wv + 4 * q + reg;
        const float xq = xsq_s[row];
        float vmax = -3.4e38f;
#pragma unroll
        for (int nt = 0; nt < 4; ++nt) {
            float v = 2.0f * acc[nt][reg] - xq - csqv[nt];
            v = fminf(v, 0.0f) * rbv[nt];
            vals[reg][nt] = v;
            vmax = fmaxf(vmax, v);
        }
#pragma unroll
        for (int off = 1; off < 16; off <<= 1)
            vmax = fmaxf(vmax, __shfl_xor(vmax, off, 64));
        float ss = 0.f;
#pragma unroll
        for (int nt = 0; nt < 4; ++nt) { vals[reg][nt] = __expf(vals[reg][nt] - vmax); ss += vals[reg][nt]; }
#pragma unroll
        for (int off = 1; off < 16; off <<= 1)
            ss += __shfl_xor(ss, off, 64);
        const float inv = 1.0f / ss;
#pragma unroll
        for (int nt = 0; nt < 4; ++nt) vals[reg][nt] *= inv;
    }

#pragma unroll
    for (int reg = 0; reg < 4; ++reg) {
        const int row = 16 * wv + 4 * q + reg;
#pragma unroll
        for (int nt = 0; nt < 4; ++nt)
            lg[row * 68 + 16 * nt + col] = vals[reg][nt];
    }
    __syncthreads();

#pragma unroll
    for (int i = 0; i < 4; ++i) {
        const int f = i * 256 + t;
        const int row = f >> 4, sp = (f & 15) * 4;
        *(f32x4*)(assign + (size_t)(n0 + row) * P_ + sp) = *(const f32x4*)&lg[row * 68 + sp];
    }

    const int p = lane;
    float v[16];
#pragma unroll
    for (int i = 0; i < 16; ++i) v[i] = lg[(wv * 16 + i) * 68 + p];
    uint4v d0, d1;
    d0.x = pk2(v[0], v[1]);   d0.y = pk2(v[2], v[3]);
    d0.z = pk2(v[4], v[5]);   d0.w = pk2(v[6], v[7]);
    d1.x = pk2(v[8], v[9]);   d1.y = pk2(v[10], v[11]);
    d1.z = pk2(v[12], v[13]); d1.w = pk2(v[14], v[15]);
    unsigned short* dst = a_t + (size_t)p * N_ + n0 + wv * 16;
    *(uint4v*)dst = d0;
    *(uint4v*)(dst + 8) = d1;
}

// ---------------------------------------------------------------------------
// group_v8: out[g,p,c] += sum_n a[n,p] x[n,c]. Grid (8 g, 8 ct, 6 splits),
// 384 blocks x 1024 rows (16 chunks of 64). Same gl_lds double-buffer
// pipeline; epilogue = direct atomicAdd into out (1.57 M atomics total,
// no partials, no reduce kernel).
// ---------------------------------------------------------------------------
__global__ __launch_bounds__(256, 3) void group_v8(
    const float* __restrict__ x, const unsigned short* __restrict__ a_t,
    float* __restrict__ out)
{
    __shared__ __align__(16) float xsb[2][64 * 64];           // 32 KB
    __shared__ __align__(16) unsigned short asb[2][64 * 64];  // 16 KB

    const int t = threadIdx.x, lane = t & 63, wv = t >> 6;
    const int q = lane >> 4, col = lane & 15;
    const int g = blockIdx.x, ct = blockIdx.y, ws = blockIdx.z;   // 0..5
    const int c0 = ct * 64;
    const int sc = ws >> 1, b0 = (ws & 1) * 1024;
    const size_t base = (size_t)sc * (G_ * B_) + (size_t)g * B_ + b0;

    const float* gx[4];
#pragma unroll
    for (int i = 0; i < 4; ++i) {
        const int n  = 16 * wv + 4 * i + (lane >> 4);
        const int pm = ((n >> 3) & 3) | (((n >> 3) & 1) << 2);
        gx[i] = x + (base + n) * C_ + c0 + (((lane & 15) ^ pm) << 2);
    }
    const unsigned short* ga[2];
#pragma unroll
    for (int i = 0; i < 2; ++i) {
        const int p = 16 * wv + 8 * i + (lane >> 3);
        ga[i] = a_t + (size_t)p * N_ + base + (((lane & 7) ^ (p & 7)) * 8);
    }
    const int cl = 16 * wv + col;
    const int permq = q | ((q & 1) << 2);
    const int cswz  = (((cl >> 2) ^ permq) << 2) | (cl & 3);
    const int ag    = col & 7;

    f32x4 acc[4];
#pragma unroll
    for (int mt = 0; mt < 4; ++mt) acc[mt] = (f32x4){0.f, 0.f, 0.f, 0.f};

#pragma unroll
    for (int i = 0; i < 4; ++i) gl_lds16(gx[i], &xsb[0][(16 * wv + 4 * i) * 64]);
#pragma unroll
    for (int i = 0; i < 2; ++i) gl_lds16(ga[i], &asb[0][(16 * wv + 8 * i) * 64]);

#pragma unroll 2
    for (int ch = 0; ch < 16; ++ch) {
        const int cur = ch & 1;
        if (ch < 15) {
            const int nb = (ch + 1) * 64;
#pragma unroll
            for (int i = 0; i < 4; ++i)
                gl_lds16(gx[i] + (size_t)nb * C_, &xsb[cur ^ 1][(16 * wv + 4 * i) * 64]);
#pragma unroll
            for (int i = 0; i < 2; ++i)
                gl_lds16(ga[i] + nb, &asb[cur ^ 1][(16 * wv + 8 * i) * 64]);
            WAIT6_BARRIER();
        } else {
            WAIT0_BARRIER();
        }
#pragma unroll
        for (int s = 0; s < 2; ++s) {
            const int koff = s * 32 + q * 8;
            float gv[8];
#pragma unroll
            for (int j = 0; j < 8; ++j) gv[j] = xsb[cur][(koff + j) * 64 + cswz];
            union { uint4v u; short8 s8; } cv;
            cv.u.x = pk2(gv[0], gv[1]); cv.u.y = pk2(gv[2], gv[3]);
            cv.u.z = pk2(gv[4], gv[5]); cv.u.w = pk2(gv[6], gv[7]);
            const int agr = 4 * s + q;
#pragma unroll
            for (int mt = 0; mt < 4; ++mt) {
                short8 af = *(const short8*)&asb[cur][(16 * mt + col) * 64 + ((agr ^ ag) * 8)];
                acc[mt] = __builtin_amdgcn_mfma_f32_16x16x32_bf16(af, cv.s8, acc[mt], 0, 0, 0);
            }
        }
        RAW_BARRIER();
    }

    // direct atomic accumulation into out (zeroed by prep2)
    float* og = out + (size_t)g * (P_ * C_);
#pragma unroll
    for (int mt = 0; mt < 4; ++mt)
#pragma unroll
        for (int reg = 0; reg < 4; ++reg) {
            const int p = 16 * mt + 4 * q + reg;
            atomicAdd(&og[p * C_ + c0 + cl], acc[mt][reg]);
        }
}

// ---------------------------------------------------------------------------
extern "C" void kernel_launch(void* const* d_in, const int* in_sizes, int n_in,
                              void* d_out, int out_size, void* d_ws, size_t ws_size,
                              hipStream_t stream) {
    const float* x  = (const float*)d_in[0];   // node_feats [3, 16384, 512]
    const float* w  = (const float*)d_in[1];   // weight [64, 512]
    const float* sf = (const float*)d_in[2];   // smooth_factor [64]

    float* out    = (float*)d_out;              // outputs [8, 64, 512]
    float* assign = out + (size_t)G_ * P_ * C_; // assign [N, 64] fp32

    unsigned short* wb    = (unsigned short*)d_ws;                   // 64 KB
    float*          csq   = (float*)((char*)d_ws + 65536);           // 256 B
    float*          rbeta = (float*)((char*)d_ws + 65792);           // 256 B
    unsigned short* a_t   = (unsigned short*)((char*)d_ws + 66048);  // 6.29 MB

    prep2_kernel<<<P_, 64, 0, stream>>>(w, sf, wb, csq, rbeta, out);
    assign_v8<<<N_ / 64, 256, 0, stream>>>(x, wb, csq, rbeta, assign, a_t);
    dim3 gridB(G_, C_ / 64, 6);
    group_v8<<<gridB, 256, 0, stream>>>(x, a_t, out);
}